// Round 1
// baseline (492.843 us; speedup 1.0000x reference)
//
#include <hip/hip_runtime.h>

#define IN_F 512
#define OUT_F 32

// ---------------------------------------------------------------------------
// GEMM: h[row][f] = sum_k x[row][k] * W[k][f] + bias[f]
// Thread-per-row, 32 fp32 accumulators, W staged in LDS in 128-row K-chunks
// (16 KB) so LDS never caps occupancy. All lanes of a wave read the same W
// element per k -> pure LDS broadcast (conflict-free). x read as float4,
// each thread streams its own row (L1/L2 catch the 64B-line reuse).
// ---------------------------------------------------------------------------
__global__ __launch_bounds__(128) void gemm_kernel(
    const float* __restrict__ x, const float* __restrict__ W,
    const float* __restrict__ bias, float* __restrict__ h, int n_rows) {
    __shared__ float Wl[128 * OUT_F];  // 16 KB
    __shared__ float bl[OUT_F];

    const int tid = threadIdx.x;
    const int row = blockIdx.x * 128 + tid;
    if (tid < OUT_F) bl[tid] = bias[tid];

    float acc[OUT_F];
#pragma unroll
    for (int f = 0; f < OUT_F; ++f) acc[f] = 0.0f;

    for (int kc = 0; kc < IN_F; kc += 128) {
        // stage W[kc..kc+128][:] -> LDS (4096 floats = 1024 float4)
        const float4* Wg = (const float4*)(W + (size_t)kc * OUT_F);
        float4* Wls = (float4*)Wl;
        for (int i = tid; i < 1024; i += 128) Wls[i] = Wg[i];
        __syncthreads();

        if (row < n_rows) {
            const float4* xr = (const float4*)(x + (size_t)row * IN_F + kc);
#pragma unroll 4
            for (int k4 = 0; k4 < 32; ++k4) {
                float4 xv = xr[k4];
#pragma unroll
                for (int kk = 0; kk < 4; ++kk) {
                    const float xs = (&xv.x)[kk];
                    const float4* wr4 =
                        (const float4*)(Wl + (k4 * 4 + kk) * OUT_F);
#pragma unroll
                    for (int f4 = 0; f4 < 8; ++f4) {
                        float4 wv = wr4[f4];
                        acc[f4 * 4 + 0] = fmaf(xs, wv.x, acc[f4 * 4 + 0]);
                        acc[f4 * 4 + 1] = fmaf(xs, wv.y, acc[f4 * 4 + 1]);
                        acc[f4 * 4 + 2] = fmaf(xs, wv.z, acc[f4 * 4 + 2]);
                        acc[f4 * 4 + 3] = fmaf(xs, wv.w, acc[f4 * 4 + 3]);
                    }
                }
            }
        }
        __syncthreads();
    }

    if (row < n_rows) {
        float4* hr = (float4*)(h + (size_t)row * OUT_F);
#pragma unroll
        for (int f4 = 0; f4 < 8; ++f4) {
            float4 o;
            o.x = acc[f4 * 4 + 0] + bl[f4 * 4 + 0];
            o.y = acc[f4 * 4 + 1] + bl[f4 * 4 + 1];
            o.z = acc[f4 * 4 + 2] + bl[f4 * 4 + 2];
            o.w = acc[f4 * 4 + 3] + bl[f4 * 4 + 3];
            hr[f4] = o;
        }
    }
}

// ---------------------------------------------------------------------------
// Edge scatter: out[dst][f] += ew[e] * h[src][f]
// Thread per (edge, feature): half-wave (32 lanes) covers one edge's 128B
// h-row (coalesced gather, L3-resident) and does 32 adjacent atomics.
// ---------------------------------------------------------------------------
__global__ __launch_bounds__(256) void edge_kernel(
    const int* __restrict__ ei, const float* __restrict__ ew,
    const float* __restrict__ h, float* __restrict__ out, int n_edges) {
    const int idx = blockIdx.x * 256 + threadIdx.x;
    const int e = idx >> 5;
    const int f = idx & 31;
    if (e < n_edges) {
        const int d = ei[e];            // dst row
        const int s = ei[n_edges + e];  // src row
        const float w = ew[e];
        const float v = w * h[(size_t)s * OUT_F + f];
        atomicAdd(out + (size_t)d * OUT_F + f, v);
    }
}

extern "C" void kernel_launch(void* const* d_in, const int* in_sizes, int n_in,
                              void* d_out, int out_size, void* d_ws,
                              size_t ws_size, hipStream_t stream) {
    const float* x = (const float*)d_in[0];
    const float* W = (const float*)d_in[1];
    const float* bias = (const float*)d_in[2];
    const float* ew = (const float*)d_in[3];
    const int* ei = (const int*)d_in[4];
    float* out = (float*)d_out;
    float* h = (float*)d_ws;  // [n_nodes][32] fp32 = 12.8 MB scratch

    const int n_nodes = in_sizes[0] / IN_F;
    const int n_edges = in_sizes[3];

    // out is re-poisoned to 0xAA before every timed launch -> zero it here.
    hipMemsetAsync(d_out, 0, (size_t)out_size * sizeof(float), stream);

    gemm_kernel<<<(n_nodes + 127) / 128, 128, 0, stream>>>(x, W, bias, h,
                                                           n_nodes);

    const long long work = (long long)n_edges * OUT_F;
    const int blocks = (int)((work + 255) / 256);
    edge_kernel<<<blocks, 256, 0, stream>>>(ei, ew, h, out, n_edges);
}